// Round 1
// baseline (188.615 us; speedup 1.0000x reference)
//
#include <hip/hip_runtime.h>

typedef _Float16 f16x8 __attribute__((ext_vector_type(8)));
typedef _Float16 f16x4 __attribute__((ext_vector_type(4)));
typedef float    f32x4 __attribute__((ext_vector_type(4)));

__device__ __forceinline__ f32x4 mfma16(f16x8 a, f16x8 b, f32x4 c) {
  return __builtin_amdgcn_mfma_f32_16x16x32_f16(a, b, c, 0, 0, 0);
}

// ---- pre-convert weights to fp16 in workspace (L2-resident reuse) ----
__global__ void cvt_weights(const float* __restrict__ qw, const float* __restrict__ cw,
                            _Float16* __restrict__ wq, _Float16* __restrict__ wc) {
  const int i = blockIdx.x * 256 + threadIdx.x;
  if (i < 384 * 128) wq[i] = (_Float16)qw[i];
  if (i < 128 * 128) wc[i] = (_Float16)cw[i];
}

// One 4x4x4 window per block. 4 waves; wave wv owns heads {2wv, 2wv+1}.
// LDS: xsm = x-window/o buffer [64 t][128 ch] f16, swizzle ^((t&15)<<4)
//      wsm[wv]: [0,4096)  qk per-head [64 t][32 ch] swz ^(((t>>2)&3)<<4), overlaid by vs [16 c][64 t] swz ^((c&7)<<4)
//               [4096,12288) P [64 t][64 s] swz ^((t&7)<<4)
__global__ void __launch_bounds__(256, 2)
win_attn(const float* __restrict__ xg, const _Float16* __restrict__ wq,
         const float* __restrict__ qb, const _Float16* __restrict__ wc,
         const float* __restrict__ cb, float* __restrict__ outg)
{
  __shared__ char xsm[16384];
  __shared__ char wsm[4][12288];

  const int tid  = threadIdx.x;
  const int lane = tid & 63;
  const int wv   = tid >> 6;
  const int l15  = lane & 15;
  const int g    = lane >> 4;

  // XCD-bijective swizzle: blocks with same (bid&7) share an XCD and get a
  // contiguous ww-range -> adjacent 16B window rows merge in that XCD's L2.
  const int raw = blockIdx.x;
  const int wid = ((raw & 7) << 9) | (raw >> 3);
  const int ww = wid & 15, hh = (wid >> 4) & 15, dd = (wid >> 8) & 7, bb = wid >> 11;

  const f32x4 fz = {0.f, 0.f, 0.f, 0.f};

  // ---------------- stage x window -> xsm (fp16, swizzled token-major) ----------------
  {
    const int m4 = lane & 3, q4 = lane >> 2;
    const int i0 = q4 >> 2, i1 = q4 & 3;
    const int z = dd * 4 + i0, y = hh * 4 + i1;
    const bool yv   = (y < 62);
    const bool full = (ww < 15);
    float va[8][4];
#pragma unroll
    for (int it = 0; it < 8; ++it) {           // issue all global loads first
      const int c = wv * 32 + it * 4 + m4;
      const float* src = xg + (((size_t)(bb * 128 + c) * 32 + (size_t)z) * 3844
                               + (size_t)(y * 62 + ww * 4));
      float a0 = 0.f, a1 = 0.f, a2 = 0.f, a3 = 0.f;
      if (yv) {
        const float2 lo = *reinterpret_cast<const float2*>(src);
        a0 = lo.x; a1 = lo.y;
        if (full) {
          const float2 hi = *reinterpret_cast<const float2*>(src + 2);
          a2 = hi.x; a3 = hi.y;
        }
      }
      va[it][0] = a0; va[it][1] = a1; va[it][2] = a2; va[it][3] = a3;
    }
#pragma unroll
    for (int it = 0; it < 8; ++it) {           // 4x4 lane-quad transpose, packed b64 write
      float v0 = va[it][0], v1 = va[it][1], v2 = va[it][2], v3 = va[it][3];
      float t0 = __shfl_xor((m4 & 1) ? v0 : v1, 1);
      float t1 = __shfl_xor((m4 & 1) ? v2 : v3, 1);
      if (m4 & 1) { v0 = t0; v2 = t1; } else { v1 = t0; v3 = t1; }
      float t2 = __shfl_xor((m4 & 2) ? v0 : v2, 2);
      float t3 = __shfl_xor((m4 & 2) ? v1 : v3, 2);
      if (m4 & 2) { v0 = t2; v1 = t3; } else { v2 = t2; v3 = t3; }
      f16x4 pk; pk[0] = (_Float16)v0; pk[1] = (_Float16)v1;
                pk[2] = (_Float16)v2; pk[3] = (_Float16)v3;
      const int c0 = wv * 32 + it * 4;         // lane now holds xs[t=lane][c0..c0+3]
      *reinterpret_cast<f16x4*>(xsm + ((lane * 256 + 2 * c0) ^ ((lane & 15) << 4))) = pk;
    }
  }
  __syncthreads();

  // ---------------- QKV GEMM: wave computes q,k,v columns of its 2 heads ----------------
  // co: 0,1 -> q(head hp=0,1); 2,3 -> k; 4,5 -> v.  col = (co>>1)*128 + wv*32 + (co&1)*16 + l15
  f32x4 acc[4][6];
#pragma unroll
  for (int i = 0; i < 4; ++i)
#pragma unroll
    for (int j = 0; j < 6; ++j) acc[i][j] = fz;

  const int swzA = l15 << 4;
#pragma unroll
  for (int kk = 0; kk < 4; ++kk) {
    f16x8 a[4];
#pragma unroll
    for (int ri = 0; ri < 4; ++ri)
      a[ri] = *reinterpret_cast<const f16x8*>(
          xsm + (ri * 16 + l15) * 256 + ((kk * 64 + g * 16) ^ swzA));
#pragma unroll
    for (int co = 0; co < 6; ++co) {
      const int col = (co >> 1) * 128 + wv * 32 + (co & 1) * 16 + l15;
      const f16x8 bfr = *reinterpret_cast<const f16x8*>(wq + col * 128 + kk * 32 + g * 8);
#pragma unroll
      for (int ri = 0; ri < 4; ++ri) acc[ri][co] = mfma16(a[ri], bfr, acc[ri][co]);
    }
  }
  // bias; fold softmax scale (hd^-0.5 = 0.25) into q
#pragma unroll
  for (int co = 0; co < 6; ++co) {
    const int col = (co >> 1) * 128 + wv * 32 + (co & 1) * 16 + l15;
    const float bias = qb[col];
    const float sc = (co < 2) ? 0.25f : 1.0f;
#pragma unroll
    for (int ri = 0; ri < 4; ++ri)
#pragma unroll
      for (int r = 0; r < 4; ++r) acc[ri][co][r] = (acc[ri][co][r] + bias) * sc;
  }
  __syncthreads();   // all waves done reading xsm -> it becomes the o buffer

  // ---------------- attention (wave-private, per head) ----------------
  char* qkb = wsm[wv];
  char* Pb  = wsm[wv] + 4096;

  unsigned long long pm = 0ull;                     // pad flag per token
  if (hh == 15) pm |= 0xFF00FF00FF00FF00ull;        // i1 >= 2
  if (ww == 15) pm |= 0xCCCCCCCCCCCCCCCCull;        // i2 >= 2

  const float LOG2E = 1.4426950408889634f;

#pragma unroll
  for (int hp = 0; hp < 2; ++hp) {
    // write q,k (this head) token-major [64][32], swz ^(((t>>2)&3)<<4) == g<<4 for writes
#pragma unroll
    for (int ri = 0; ri < 4; ++ri)
#pragma unroll
      for (int r = 0; r < 4; ++r) {
        const int t  = ri * 16 + g * 4 + r;
        const int sw = ((t >> 2) & 3) << 4;
        *reinterpret_cast<_Float16*>(qkb + t * 64 + ((2 * l15) ^ sw))        = (_Float16)acc[ri][hp][r];
        *reinterpret_cast<_Float16*>(qkb + t * 64 + ((32 + 2 * l15) ^ sw))   = (_Float16)acc[ri][2 + hp][r];
      }

    // S^T = k @ q^T  (K=32, upper 16 zero-padded)
    f16x8 ka[4], qa[4];
    const int swq = ((l15 >> 2) & 3) << 4;
#pragma unroll
    for (int ri = 0; ri < 4; ++ri) {
      f16x8 kz, qz;
      if (g < 2) {
        const int row = ri * 16 + l15;
        kz = *reinterpret_cast<const f16x8*>(qkb + row * 64 + ((32 + g * 16) ^ swq));
        qz = *reinterpret_cast<const f16x8*>(qkb + row * 64 + ((g * 16) ^ swq));
      } else {
#pragma unroll
        for (int e = 0; e < 8; ++e) { kz[e] = (_Float16)0.f; qz[e] = (_Float16)0.f; }
      }
      ka[ri] = kz; qa[ri] = qz;
    }
    f32x4 st[4][4];
#pragma unroll
    for (int ri = 0; ri < 4; ++ri)
#pragma unroll
      for (int cj = 0; cj < 4; ++cj) st[ri][cj] = mfma16(ka[ri], qa[cj], fz);

    // pad mask: -1000 where pad(s) != pad(t)
    if (pm) {
#pragma unroll
      for (int cj = 0; cj < 4; ++cj) {
        const int t = cj * 16 + l15;
        const unsigned ft = (unsigned)(pm >> t) & 1u;
#pragma unroll
        for (int ri = 0; ri < 4; ++ri)
#pragma unroll
          for (int r = 0; r < 4; ++r) {
            const int s = ri * 16 + g * 4 + r;
            const unsigned fs = (unsigned)(pm >> s) & 1u;
            if (fs != ft) st[ri][cj][r] -= 1000.f;
          }
      }
    }

    // softmax over s: 16 lane-local values per cj + 2 shfl (g groups)
#pragma unroll
    for (int cj = 0; cj < 4; ++cj) {
      float mx = st[0][cj][0];
#pragma unroll
      for (int ri = 0; ri < 4; ++ri)
#pragma unroll
        for (int r = 0; r < 4; ++r) mx = fmaxf(mx, st[ri][cj][r]);
      mx = fmaxf(mx, __shfl_xor(mx, 16));
      mx = fmaxf(mx, __shfl_xor(mx, 32));
      float sum = 0.f;
#pragma unroll
      for (int ri = 0; ri < 4; ++ri)
#pragma unroll
        for (int r = 0; r < 4; ++r) {
          const float e = __builtin_amdgcn_exp2f((st[ri][cj][r] - mx) * LOG2E);
          st[ri][cj][r] = e; sum += e;
        }
      sum += __shfl_xor(sum, 16);
      sum += __shfl_xor(sum, 32);
      const float inv = __builtin_amdgcn_rcpf(sum);
#pragma unroll
      for (int ri = 0; ri < 4; ++ri)
#pragma unroll
        for (int r = 0; r < 4; ++r) st[ri][cj][r] *= inv;
    }

    // write P [t][s] (b64 packed), and v^T [c][t] overlaying qk region
#pragma unroll
    for (int cj = 0; cj < 4; ++cj) {
      const int t   = cj * 16 + l15;
      const int swp = (t & 7) << 4;
#pragma unroll
      for (int ri = 0; ri < 4; ++ri) {
        f16x4 pk; pk[0] = (_Float16)st[ri][cj][0]; pk[1] = (_Float16)st[ri][cj][1];
                  pk[2] = (_Float16)st[ri][cj][2]; pk[3] = (_Float16)st[ri][cj][3];
        *reinterpret_cast<f16x4*>(Pb + t * 128 + ((ri * 32 + g * 8) ^ swp)) = pk;
      }
    }
    {
      const int swv = (l15 & 7) << 4;
#pragma unroll
      for (int ri = 0; ri < 4; ++ri) {
        f16x4 pk; pk[0] = (_Float16)acc[ri][4 + hp][0]; pk[1] = (_Float16)acc[ri][4 + hp][1];
                  pk[2] = (_Float16)acc[ri][4 + hp][2]; pk[3] = (_Float16)acc[ri][4 + hp][3];
        *reinterpret_cast<f16x4*>(qkb + l15 * 128 + ((ri * 32 + g * 8) ^ swv)) = pk;
      }
    }

    // PV: o[t][c] = P @ v   (K = 64, 2 steps)
    f32x4 oacc[4];
#pragma unroll
    for (int ri = 0; ri < 4; ++ri) oacc[ri] = fz;
    const int swp2 = (l15 & 7) << 4;
#pragma unroll
    for (int k2 = 0; k2 < 2; ++k2) {
      const f16x8 pb = *reinterpret_cast<const f16x8*>(
          qkb + l15 * 128 + ((k2 * 64 + g * 16) ^ swp2));
#pragma unroll
      for (int ri = 0; ri < 4; ++ri) {
        const f16x8 pa = *reinterpret_cast<const f16x8*>(
            Pb + (ri * 16 + l15) * 128 + ((k2 * 64 + g * 16) ^ swp2));
        oacc[ri] = mfma16(pa, pb, oacc[ri]);
      }
    }
    // o -> shared buffer (reused xsm), channel = head*16 + l15
    const int ch = (2 * wv + hp) * 16 + l15;
#pragma unroll
    for (int ri = 0; ri < 4; ++ri)
#pragma unroll
      for (int r = 0; r < 4; ++r) {
        const int t = ri * 16 + g * 4 + r;
        *reinterpret_cast<_Float16*>(xsm + t * 256 + ((2 * ch) ^ ((t & 15) << 4)))
            = (_Float16)oacc[ri][r];
      }
  }
  __syncthreads();

  // ---------------- 1x1x1 conv GEMM + store ----------------
  f32x4 cacc[4][2];
#pragma unroll
  for (int i = 0; i < 4; ++i) { cacc[i][0] = fz; cacc[i][1] = fz; }
#pragma unroll
  for (int kk = 0; kk < 4; ++kk) {
    f16x8 a[4];
#pragma unroll
    for (int ri = 0; ri < 4; ++ri)
      a[ri] = *reinterpret_cast<const f16x8*>(
          xsm + (ri * 16 + l15) * 256 + ((kk * 64 + g * 16) ^ swzA));
#pragma unroll
    for (int co = 0; co < 2; ++co) {
      const int cout = wv * 32 + co * 16 + l15;
      const f16x8 bfr = *reinterpret_cast<const f16x8*>(wc + cout * 128 + kk * 32 + g * 8);
#pragma unroll
      for (int ri = 0; ri < 4; ++ri) cacc[ri][co] = mfma16(a[ri], bfr, cacc[ri][co]);
    }
  }
  // rows: t = ri*16 + g*4 + r  ->  i0 = ri (z), i1 = g (y), i2 = r (x): contiguous stores
  const int y = hh * 4 + g;
  if (y < 62) {
#pragma unroll
    for (int co = 0; co < 2; ++co) {
      const int cout = wv * 32 + co * 16 + l15;
      const float bias = cb[cout];
#pragma unroll
      for (int ri = 0; ri < 4; ++ri) {
        const int z = dd * 4 + ri;
        float* dst = outg + (((size_t)(bb * 128 + cout) * 32 + (size_t)z) * 3844
                             + (size_t)(y * 62 + ww * 4));
        float2 lo; lo.x = cacc[ri][co][0] + bias; lo.y = cacc[ri][co][1] + bias;
        *reinterpret_cast<float2*>(dst) = lo;
        if (ww < 15) {
          float2 hi; hi.x = cacc[ri][co][2] + bias; hi.y = cacc[ri][co][3] + bias;
          *reinterpret_cast<float2*>(dst + 2) = hi;
        }
      }
    }
  }
}

extern "C" void kernel_launch(void* const* d_in, const int* in_sizes, int n_in,
                              void* d_out, int out_size, void* d_ws, size_t ws_size,
                              hipStream_t stream) {
  const float* x  = (const float*)d_in[0];
  const float* qw = (const float*)d_in[1];
  const float* qb = (const float*)d_in[2];
  const float* cw = (const float*)d_in[3];
  const float* cb = (const float*)d_in[4];
  float* out = (float*)d_out;

  if (ws_size < (size_t)(384 * 128 + 128 * 128) * sizeof(_Float16)) return;
  _Float16* wq = (_Float16*)d_ws;
  _Float16* wc = wq + 384 * 128;

  cvt_weights<<<192, 256, 0, stream>>>(qw, cw, wq, wc);
  win_attn<<<4096, 256, 0, stream>>>(x, wq, qb, wc, cb, out);
}